// Round 1
// baseline (251.390 us; speedup 1.0000x reference)
//
#include <hip/hip_runtime.h>

// SKA3D: x [B=2, C=64, D=64, H=64, W=64] fp32; w [B=2, G=8, 27, D, H, W] fp32
// out[b,c,d,h,w] = sum_k x[b,c,(d+di)%D,(h+hi)%H,(w+wi)%W] * w[b,c/8,k,d,h,w]
// k = (di+1)*9 + (hi+1)*3 + (wi+1), taps in {-1,0,1}^3 (circular).

#define NB 2
#define NC 64
#define NG 8
#define CPG 8
#define ND 64
#define NH 64
#define NW 64
#define HW (NH * NW)        // 4096
#define DHW (ND * NH * NW)  // 262144

__global__ __launch_bounds__(256) void ska3d_kernel(const float* __restrict__ x,
                                                    const float* __restrict__ w,
                                                    float* __restrict__ out) {
    const int tid = threadIdx.x;
    const int ww0 = tid & 63;        // w position
    const int hl  = tid >> 6;        // 0..3
    const int bid = blockIdx.x;
    const int h4 = bid & 15;         // H/4 = 16
    const int d  = (bid >> 4) & 63;
    const int g  = (bid >> 10) & 7;
    const int b  = bid >> 13;
    const int h  = h4 * 4 + hl;

    // w tap pointer at this output position; tap stride = DHW
    const float* wp = w + ((size_t)(b * NG + g) * 27) * DHW + (size_t)d * HW + h * NW + ww0;
    // x base for channel group
    const float* xb = x + (size_t)(b * NC + g * CPG) * DHW;

    float acc[CPG];
#pragma unroll
    for (int c = 0; c < CPG; ++c) acc[c] = 0.f;

#pragma unroll
    for (int di = -1; di <= 1; ++di) {
        const int dd = (d + di) & 63;
#pragma unroll
        for (int hi = -1; hi <= 1; ++hi) {
            const int hh = (h + hi) & 63;
#pragma unroll
            for (int wi = -1; wi <= 1; ++wi) {
                const int wwi = (ww0 + wi) & 63;
                const int k = (di + 1) * 9 + (hi + 1) * 3 + (wi + 1);
                const float wk = wp[(size_t)k * DHW];
                const int xoff = dd * HW + hh * NW + wwi;
#pragma unroll
                for (int c = 0; c < CPG; ++c)
                    acc[c] += wk * xb[(size_t)c * DHW + xoff];
            }
        }
    }

    float* op = out + (size_t)(b * NC + g * CPG) * DHW + (size_t)d * HW + h * NW + ww0;
#pragma unroll
    for (int c = 0; c < CPG; ++c) op[(size_t)c * DHW] = acc[c];
}

extern "C" void kernel_launch(void* const* d_in, const int* in_sizes, int n_in,
                              void* d_out, int out_size, void* d_ws, size_t ws_size,
                              hipStream_t stream) {
    const float* x = (const float*)d_in[0];
    const float* w = (const float*)d_in[1];
    float* out = (float*)d_out;
    // grid: B * G * D * (H/4) = 2*8*64*16 = 16384 blocks of 256 threads
    dim3 grid(NB * NG * ND * (NH / 4));
    dim3 block(256);
    hipLaunchKernelGGL(ska3d_kernel, grid, block, 0, stream, x, w, out);
}

// Round 2
// 248.824 us; speedup vs baseline: 1.0103x; 1.0103x over previous
//
#include <hip/hip_runtime.h>

// SKA3D: x [B=2, C=64, D=64, H=64, W=64] fp32; w [B=2, G=8, 27, D, H, W] fp32
// out[b,c,d,h,w] = sum_k x[b,c,(d+di)%64,(h+hi)%64,(w+wi)%64] * w[b,c/8,k,d,h,w]
// Each thread: one (b,g,d,h) and a 4-wide W strip, all 8 channels of the group.
// w loads amortized over 8 channels; x row loads (float4 + 2 halo scalars)
// amortized over the 3 wi taps.

#define NB 2
#define NG 8
#define CPG 8
#define ND 64
#define NH 64
#define NW 64
#define HW (NH * NW)        // 4096
#define DHW (ND * NH * NW)  // 262144

__global__ __launch_bounds__(256) void ska3d_kernel(const float* __restrict__ x,
                                                    const float* __restrict__ w,
                                                    float* __restrict__ out) {
    const int tid = threadIdx.x;
    const int w0 = (tid & 15) * 4;   // W strip start: 0,4,...,60
    const int hl = tid >> 4;         // 0..15
    const int bid = blockIdx.x;
    const int h0 = (bid & 3) * 16;   // 4 blocks cover H=64
    const int d  = (bid >> 2) & 63;
    const int g  = (bid >> 8) & 7;
    const int b  = bid >> 11;
    const int h  = h0 + hl;

    const float* wp = w + ((size_t)(b * NG + g) * 27) * DHW + (size_t)d * HW + h * NW + w0;
    const float* xb = x + (size_t)(b * 64 + g * CPG) * DHW;

    float acc[CPG][4];
#pragma unroll
    for (int c = 0; c < CPG; ++c)
#pragma unroll
        for (int j = 0; j < 4; ++j) acc[c][j] = 0.f;

    const int wl = (w0 + 63) & 63;   // left halo index (circular)
    const int wr = (w0 + 4) & 63;    // right halo index (circular)

#pragma unroll
    for (int di = -1; di <= 1; ++di) {
        const int dd = (d + di) & 63;
#pragma unroll
        for (int hi = -1; hi <= 1; ++hi) {
            const int hh = (h + hi) & 63;
            const int rowbase = dd * HW + hh * NW;

            float4 xv[CPG];
            float  xlo[CPG], xhi[CPG];
#pragma unroll
            for (int c = 0; c < CPG; ++c) {
                const float* xrow = xb + (size_t)c * DHW + rowbase;
                xv[c]  = *(const float4*)(xrow + w0);
                xlo[c] = xrow[wl];
                xhi[c] = xrow[wr];
            }

#pragma unroll
            for (int wi = -1; wi <= 1; ++wi) {
                const int k = (di + 1) * 9 + (hi + 1) * 3 + (wi + 1);
                const float4 wk = *(const float4*)(wp + (size_t)k * DHW);
#pragma unroll
                for (int c = 0; c < CPG; ++c) {
                    float o0, o1, o2, o3;
                    if (wi == -1)      { o0 = xlo[c];  o1 = xv[c].x; o2 = xv[c].y; o3 = xv[c].z; }
                    else if (wi == 0)  { o0 = xv[c].x; o1 = xv[c].y; o2 = xv[c].z; o3 = xv[c].w; }
                    else               { o0 = xv[c].y; o1 = xv[c].z; o2 = xv[c].w; o3 = xhi[c]; }
                    acc[c][0] += wk.x * o0;
                    acc[c][1] += wk.y * o1;
                    acc[c][2] += wk.z * o2;
                    acc[c][3] += wk.w * o3;
                }
            }
        }
    }

    float* op = out + (size_t)(b * 64 + g * CPG) * DHW + (size_t)d * HW + h * NW + w0;
#pragma unroll
    for (int c = 0; c < CPG; ++c) {
        float4 v = make_float4(acc[c][0], acc[c][1], acc[c][2], acc[c][3]);
        *(float4*)(op + (size_t)c * DHW) = v;
    }
}

extern "C" void kernel_launch(void* const* d_in, const int* in_sizes, int n_in,
                              void* d_out, int out_size, void* d_ws, size_t ws_size,
                              hipStream_t stream) {
    const float* x = (const float*)d_in[0];
    const float* w = (const float*)d_in[1];
    float* out = (float*)d_out;
    // grid: B * G * D * (H/16) = 2*8*64*4 = 4096 blocks of 256 threads
    dim3 grid(NB * NG * ND * 4);
    dim3 block(256);
    hipLaunchKernelGGL(ska3d_kernel, grid, block, 0, stream, x, w, out);
}

// Round 3
// 178.558 us; speedup vs baseline: 1.4079x; 1.3935x over previous
//
#include <hip/hip_runtime.h>

// SKA3D: x [B=2, C=64, D=64, H=64, W=64] fp32; w [B=2, G=8, 27, D, H, W] fp32
// out[b,c,d,h,w] = sum_k x[b,c,(d+di)%64,(h+hi)%64,(w+wi)%64] * w[b,c/8,k,d,h,w]
//
// R3 design: single-wave blocks (64 thr = 16 w-strips x 4 h), d-sliding LDS ring.
//  - LDS: 4 slots x 8ch x 6 h-rows x 64 w  = 48 KB (3 blocks/CU resident)
//  - staging: global_load_lds width=16, linear LDS dest (base + lane*16)
//  - ring hazard: slot (d+2)&3 is disjoint from read slots (d-1,d,d+1)&3
//  - sync: pure s_waitcnt vmcnt(N), no barriers (single wave)
//    steady-state wait vmcnt(47) = stores(8) + stage(12) + w-loads(27) newer
//    than the stage batch we must drain.

#define ND 64
#define NH 64
#define NW 64
#define HW 4096
#define DHW 262144
#define CPG 8

typedef const __attribute__((address_space(1))) unsigned int* gp_as1;
typedef __attribute__((address_space(3))) unsigned int* lp_as3;

__global__ __launch_bounds__(64, 1) void ska3d_kernel(const float* __restrict__ x,
                                                      const float* __restrict__ w,
                                                      float* __restrict__ out) {
    __shared__ float lds[4][CPG][6][NW];   // [slot][c][r][w] 48 KB

    const int lane = threadIdx.x;          // 0..63
    const int w0   = (lane & 15) * 4;      // w strip start
    const int hl   = lane >> 4;            // 0..3

    const int bid = blockIdx.x;
    const int dc  = bid & 7;               // d-chunk (8 planes each)
    const int ht  = (bid >> 3) & 15;       // h-tile (4 rows each)
    const int g   = (bid >> 7) & 7;
    const int b   = bid >> 10;

    const int d0 = dc * 8;
    const int h0 = ht * 4;
    const int h  = h0 + hl;

    const float* xb = x + (size_t)(b * 64 + g * CPG) * DHW;
    const float* wb = w + (size_t)(b * 8 + g) * 27 * DHW;
    float* ob = out + (size_t)(b * 64 + g * CPG) * DHW + h * NW + w0;

    const int wlb = (w0 + 60) & 63;        // left b128 (gives x[w0-1] in .w)
    const int wrb = (w0 + 4) & 63;         // right b128 (gives x[w0+4] in .x)

    // stage plane p (UNWRAPPED index; slot = p&3, global dd = p&63)
    // plane = 8c x 6r x 64w floats = 12 KB = 12 calls x (64 lanes x 16 B)
#define STAGE(p) do {                                                          \
        const int slot_ = (p) & 3;                                             \
        const int dd_   = (p) & 63;                                            \
        _Pragma("unroll")                                                      \
        for (int i = 0; i < 12; ++i) {                                         \
            const int fid = i * 64 + lane;     /* 16B unit id, 0..767 */       \
            const int c_  = fid / 96;          /* 96 units per channel  */     \
            const int rm_ = fid - c_ * 96;                                     \
            const int r_  = rm_ >> 4;          /* 0..5 */                      \
            const int ws_ = rm_ & 15;          /* 0..15 */                     \
            const int hh_ = (h0 - 1 + r_) & 63;                                \
            const float* gsrc = xb + (size_t)c_ * DHW + dd_ * HW + hh_ * NW + ws_ * 4; \
            __builtin_amdgcn_global_load_lds((gp_as1)gsrc,                     \
                (lp_as3)&lds[slot_][c_][r_][ws_ * 4], 16, 0, 0);               \
        }                                                                      \
    } while (0)

    // prologue: planes d0-1, d0, d0+1; full drain
    STAGE(d0 - 1);
    STAGE(d0);
    STAGE(d0 + 1);
    asm volatile("s_waitcnt vmcnt(0)" ::: "memory");

    for (int d = d0; d < d0 + 8; ++d) {
        STAGE(d + 2);   // into slot (d+2)&3 — disjoint from read slots

        // dynamic weights: 27 taps x float4, hoisted for MLP
        float4 wk[27];
        const float* wpd = wb + (size_t)d * HW + h * NW + w0;
#pragma unroll
        for (int k = 0; k < 27; ++k)
            wk[k] = *(const float4*)(wpd + (size_t)k * DHW);

        // drain stage(d+1) (issued last step): everything newer = 8+12+27
        asm volatile("s_waitcnt vmcnt(47)" ::: "memory");

        float acc[CPG][4];
#pragma unroll
        for (int c = 0; c < CPG; ++c)
            acc[c][0] = acc[c][1] = acc[c][2] = acc[c][3] = 0.f;

#pragma unroll
        for (int di = -1; di <= 1; ++di) {
            const int slot = (d + di) & 3;
#pragma unroll
            for (int hi = -1; hi <= 1; ++hi) {
                const int r  = hl + hi + 1;          // 0..5
                const int kb = (di + 1) * 9 + (hi + 1) * 3;
#pragma unroll
                for (int c = 0; c < CPG; ++c) {
                    const float* row = &lds[slot][c][r][0];
                    const float4 xm = *(const float4*)(row + wlb);
                    const float4 xv = *(const float4*)(row + w0);
                    const float4 xp = *(const float4*)(row + wrb);
                    const float4 wa = wk[kb], wm = wk[kb + 1], wc = wk[kb + 2];
                    acc[c][0] += wa.x * xm.w;  acc[c][1] += wa.y * xv.x;
                    acc[c][2] += wa.z * xv.y;  acc[c][3] += wa.w * xv.z;
                    acc[c][0] += wm.x * xv.x;  acc[c][1] += wm.y * xv.y;
                    acc[c][2] += wm.z * xv.z;  acc[c][3] += wm.w * xv.w;
                    acc[c][0] += wc.x * xv.y;  acc[c][1] += wc.y * xv.z;
                    acc[c][2] += wc.z * xv.w;  acc[c][3] += wc.w * xp.x;
                }
            }
        }

#pragma unroll
        for (int c = 0; c < CPG; ++c)
            *(float4*)(ob + (size_t)c * DHW + (size_t)d * HW) =
                make_float4(acc[c][0], acc[c][1], acc[c][2], acc[c][3]);
    }
}

extern "C" void kernel_launch(void* const* d_in, const int* in_sizes, int n_in,
                              void* d_out, int out_size, void* d_ws, size_t ws_size,
                              hipStream_t stream) {
    const float* x = (const float*)d_in[0];
    const float* w = (const float*)d_in[1];
    float* out = (float*)d_out;
    // grid: b(2) x g(8) x h-tiles(16) x d-chunks(8) = 2048 single-wave blocks
    dim3 grid(2048);
    dim3 block(64);
    hipLaunchKernelGGL(ska3d_kernel, grid, block, 0, stream, x, w, out);
}